// Round 6
// baseline (382.721 us; speedup 1.0000x reference)
//
#include <hip/hip_runtime.h>

// ProtoNet: out[q][n] = -|| (xq[q]@W + b) - proto[n] ||^2
// v6: BK=128 (half the barriers) + A-path via DMA from pre-converted bf16 xq.
//   k_prep : transpose W -> Wt bf16; zero out+pnorm_part; bin ys;
//            blocks 257.. convert xq f32 -> xqb bf16 (if workspace allows)
//   k1_csum: per-class support sums (f32)            -> csum [64][2048]
//   k2_full: proto = csum@W/cnt + b in one shot      -> proto_bf + pnorm_part
//   k3_fused<ADMA>: z = xq@W + b (128x128 tile, BK=128, 4 waves, DMA staging)
//            + fused distance epilogue, atomicAdd into pre-zeroed out.

typedef __attribute__((ext_vector_type(8))) short short8;
typedef __attribute__((ext_vector_type(4))) float floatx4;

#define S_ROWS 1024
#define F_DIM  2048
#define D_DIM  512
#define NWAY   64
#define Q_ROWS 16384
#define ZS_LD  136

static __device__ __forceinline__ unsigned short f2bf(float f) {
  unsigned int u = __float_as_uint(f);
  u += 0x7FFF + ((u >> 16) & 1);   // RNE
  return (unsigned short)(u >> 16);
}
static __device__ __forceinline__ float bf2f(unsigned short s) {
  return __uint_as_float(((unsigned int)s) << 16);
}
// pack two floats -> two bf16 (round-half-up; ties-only deviation from RNE)
static __device__ __forceinline__ unsigned int pack_bf2(float x, float y) {
  unsigned int ux = __float_as_uint(x) + 0x8000u;
  unsigned int uy = __float_as_uint(y) + 0x8000u;
  return __builtin_amdgcn_perm(uy, ux, 0x07060302u);  // hi16(uy)<<16 | hi16(ux)
}
// async global->LDS, 16B per lane. LDS dest = wave-uniform base + lane*16.
static __device__ __forceinline__ void load_lds16(const unsigned short* g, unsigned short* l) {
  __builtin_amdgcn_global_load_lds((const __attribute__((address_space(1))) unsigned int*)g,
                                   (__attribute__((address_space(3))) unsigned int*)l,
                                   16, 0, 0);
}

// ---- k_prep: blocks 0..255 transpose W + zero their slice of out;
//      block 256 bins support ids + zeroes pnorm_part; blocks 257.. cvt xq ----
__global__ __launch_bounds__(256) void k_prep(const float* __restrict__ W,
                                              unsigned short* __restrict__ Wt,
                                              float* __restrict__ outz,
                                              float* __restrict__ pnorm_part,
                                              const int* __restrict__ ys,
                                              int* __restrict__ order,
                                              int* __restrict__ starts,
                                              float* __restrict__ counts,
                                              const float* __restrict__ xq,
                                              unsigned short* __restrict__ xqb) {
  __shared__ unsigned short t[64][65];
  __shared__ int cnt[NWAY];
  __shared__ int st[NWAY + 1];
  __shared__ int wp[NWAY];
  int bx = blockIdx.x;
  int tid = threadIdx.x;
  if (bx >= 257) {
    // xq f32 -> bf16 (round-half-up, identical to the old in-loop pack path).
    // 4096 blocks x 256 thr x 32 elems = 33,554,432 = 16384*2048.
    size_t base = (size_t)(bx - 257) * 8192 + (size_t)tid * 32;
#pragma unroll
    for (int u = 0; u < 4; u++) {
      float4 v0 = *(const float4*)&xq[base + u * 8];
      float4 v1 = *(const float4*)&xq[base + u * 8 + 4];
      uint4 w;
      w.x = pack_bf2(v0.x, v0.y); w.y = pack_bf2(v0.z, v0.w);
      w.z = pack_bf2(v1.x, v1.y); w.w = pack_bf2(v1.z, v1.w);
      *(uint4*)&xqb[base + u * 8] = w;
    }
    return;
  }
  if (bx < 256) {
    // zero this block's slice of out (16384*64 f32 total)
    float4 zz = {0.f, 0.f, 0.f, 0.f};
#pragma unroll
    for (int p = 0; p < 4; p++)
      *(float4*)&outz[(size_t)bx * 4096 + p * 1024 + tid * 4] = zz;
    int f0 = (bx >> 3) << 6;   // 32 f-tiles
    int d0 = (bx & 7) << 6;    // 8 d-tiles
    for (int j = 0; j < 16; j++) {
      int lin = j * 256 + tid;
      int fl = lin >> 6, dl = lin & 63;
      t[fl][dl] = f2bf(W[(size_t)(f0 + fl) * D_DIM + d0 + dl]);
    }
    __syncthreads();
    for (int j = 0; j < 16; j++) {
      int lin = j * 256 + tid;
      int dl = lin >> 6, fl = lin & 63;
      Wt[(size_t)(d0 + dl) * F_DIM + f0 + fl] = t[fl][dl];
    }
  } else {
    pnorm_part[tid] = 0.f;   // 256 entries = [4 slices][64 classes]
    if (tid < NWAY) cnt[tid] = 0;
    __syncthreads();
    for (int j = tid; j < S_ROWS; j += 256) atomicAdd(&cnt[ys[j]], 1);
    __syncthreads();
    if (tid == 0) {
      int a = 0;
      for (int c = 0; c < NWAY; c++) { st[c] = a; wp[c] = a; a += cnt[c]; }
      st[NWAY] = a;
    }
    __syncthreads();
    for (int j = tid; j < S_ROWS; j += 256) {
      int c = ys[j];
      int p = atomicAdd(&wp[c], 1);
      order[p] = j;
    }
    if (tid < NWAY) counts[tid] = (float)cnt[tid];
    if (tid < NWAY + 1) starts[tid] = st[tid];
  }
}

// ---- K1: class sums. grid = 64 classes x 2 f-tiles; float4 per thread ----
__global__ __launch_bounds__(256) void k1_csum(const float* __restrict__ xs,
                                               const int* __restrict__ order,
                                               const int* __restrict__ starts,
                                               float* __restrict__ csum) {
  __shared__ int lord[S_ROWS];
  int c = blockIdx.x >> 1;
  int tid = threadIdx.x;
  int s = starts[c], e = starts[c + 1];
  int len = e - s;
  for (int j = tid; j < len; j += 256) lord[j] = order[s + j];
  __syncthreads();
  int f0 = (blockIdx.x & 1) * 1024 + tid * 4;
  float4 a = {0.f, 0.f, 0.f, 0.f};
  for (int i = 0; i < len; i++) {
    float4 v = *(const float4*)&xs[(size_t)lord[i] * F_DIM + f0];
    a.x += v.x; a.y += v.y; a.z += v.z; a.w += v.w;
  }
  *(float4*)&csum[(size_t)c * F_DIM + f0] = a;
}

// ---- k2_full: proto in one shot. grid = 8 class-groups x 8 d-chunks = 64. ----
__global__ __launch_bounds__(256) void k2_full(const float* __restrict__ W,
                                               const float* __restrict__ csum,
                                               const float* __restrict__ b,
                                               const float* __restrict__ counts,
                                               unsigned short* __restrict__ proto_bf,
                                               float* __restrict__ pnorm_part) {
  __shared__ __align__(16) float wch[64 * 64];   // 16 KB
  __shared__ float csl[8 * 64];                  // 2 KB
  int bx = blockIdx.x;
  int cg = bx >> 3, dc = bx & 7;
  int c0 = cg * 8, d0 = dc * 64;
  int tid = threadIdx.x;
  int cl = tid >> 5;          // local class 0..7
  int dl = (tid & 31) * 2;    // local d col pair
  float a0 = 0.f, a1 = 0.f;
  for (int fs = 0; fs < 32; fs++) {
    int f0 = fs * 64;
    __syncthreads();
    for (int idx = tid; idx < 4096; idx += 256) {
      int r = idx >> 6, q = idx & 63;
      wch[idx] = W[(size_t)(f0 + r) * D_DIM + d0 + q];
    }
    for (int idx = tid; idx < 512; idx += 256) {
      int r = idx >> 6, q = idx & 63;
      csl[idx] = csum[(size_t)(c0 + r) * F_DIM + f0 + q];
    }
    __syncthreads();
#pragma unroll 8
    for (int f = 0; f < 64; f++) {
      float s = csl[cl * 64 + f];
      a0 += s * wch[f * 64 + dl];
      a1 += s * wch[f * 64 + dl + 1];
    }
  }
  int c = c0 + cl;
  float cntv = counts[c];
  float inv = 1.f / fmaxf(cntv, 1.f);
  float p0 = (a0 + cntv * b[d0 + dl]) * inv;     // cnt==0 -> 0, matches ref
  float p1 = (a1 + cntv * b[d0 + dl + 1]) * inv;
  unsigned short h0 = f2bf(p0), h1 = f2bf(p1);
  proto_bf[(size_t)c * D_DIM + d0 + dl] = h0;
  proto_bf[(size_t)c * D_DIM + d0 + dl + 1] = h1;
  float q0 = bf2f(h0), q1 = bf2f(h1);
  float s2 = q0 * q0 + q1 * q1;
  s2 += __shfl_xor(s2, 1, 32);
  s2 += __shfl_xor(s2, 2, 32);
  s2 += __shfl_xor(s2, 4, 32);
  s2 += __shfl_xor(s2, 8, 32);
  s2 += __shfl_xor(s2, 16, 32);
  if ((tid & 31) == 0) atomicAdd(&pnorm_part[(dc >> 1) * 64 + c], s2);
}

// ---- k3_fused<ADMA>: 128x128 z-tile GEMM, BK=128 (16 K-steps, 2 barriers
//      each), 4 waves (each 64x64). ADMA=1: A via global_load_lds from bf16
//      xqb. ADMA=0: A via f32 load + pack (fallback if ws too small).
//      grid = 128 m-tiles x 4 n-slices = 512 blocks. Fused distance epilogue. ----
template <int ADMA>
__global__ __launch_bounds__(256) void k3_fused(const float* __restrict__ xq,
                                                const unsigned short* __restrict__ xqb,
                                                const unsigned short* __restrict__ Wt,
                                                const float* __restrict__ b,
                                                const unsigned short* __restrict__ proto_bf,
                                                const float* __restrict__ pnorm_part,
                                                float* __restrict__ out) {
  // LDS: lA [128][128] halfs 32K + lB 32K = 64K; epilogue overlays zs (34816B)
  // on the same region; qnf/pnl at tail. Total 66304 -> 2 blocks/CU.
  __shared__ __align__(16) char smem[66304];
  unsigned short* lA = (unsigned short*)smem;
  unsigned short* lB = (unsigned short*)(smem + 32768);
  unsigned short* zs = (unsigned short*)smem;      // 128 x ZS_LD halfs
  float* qnf = (float*)(smem + 65536);             // 128
  float* pnl = (float*)(smem + 66048);             // 64

  int tid = threadIdx.x;
  int bx = blockIdx.x;
  // XCD swizzle (512 % 8 == 0, bijective): 4 n-slices of one m-tile are
  // dispatch-neighbors on the same XCD -> L2 reuse of the A-tile.
  int xcd = bx & 7;
  int wg = xcd * 64 + (bx >> 3);
  int mt = wg >> 2;                 // 0..127
  int slice = wg & 3;
  int n0 = slice * 128;
  int m0 = mt * 128;

  int wave = tid >> 6, lane = tid & 63;
  int wr = wave >> 1, wc = wave & 1;   // wave-grid 2x2; wave tile 64x64
  int lrow = lane & 15, lquad = lane >> 4;

  floatx4 acc[4][4];
#pragma unroll
  for (int i = 0; i < 4; i++)
#pragma unroll
    for (int j = 0; j < 4; j++) acc[i][j] = (floatx4){0.f, 0.f, 0.f, 0.f};

  // staging maps (BK=128): chunk ch = i*256 + tid, i=0..7; row = ch>>4
  // (16 chunks of 16B per 256B row), colq = ch&15. LDS linear = ch*16B.
  int srow = tid >> 4, scolq = tid & 15;
  const unsigned short* ag =
      ADMA ? xqb + (size_t)(m0 + srow) * F_DIM + scolq * 8 : (const unsigned short*)0;
  const unsigned short* bg = Wt + (size_t)(n0 + srow) * F_DIM + scolq * 8;
  const float* agf =
      ADMA ? (const float*)0 : xq + (size_t)(m0 + srow) * F_DIM + scolq * 8;

  for (int k0 = 0; k0 < F_DIM; k0 += 128) {
    // B: async global->LDS
#pragma unroll
    for (int i = 0; i < 8; i++)
      load_lds16(bg + (size_t)i * 16 * F_DIM + k0, &lB[(i * 256 + wave * 64) * 8]);
    if constexpr (ADMA) {
      // A: async global->LDS from bf16
#pragma unroll
      for (int i = 0; i < 8; i++)
        load_lds16(ag + (size_t)i * 16 * F_DIM + k0, &lA[(i * 256 + wave * 64) * 8]);
    } else {
      // A: f32 global -> regs -> pack bf16 -> LDS
#pragma unroll
      for (int p = 0; p < 8; p++) {
        const float* gp = agf + (size_t)p * 16 * F_DIM + k0;
        float4 v0 = *(const float4*)gp;
        float4 v1 = *(const float4*)(gp + 4);
        uint4 w;
        w.x = pack_bf2(v0.x, v0.y); w.y = pack_bf2(v0.z, v0.w);
        w.z = pack_bf2(v1.x, v1.y); w.w = pack_bf2(v1.z, v1.w);
        *(uint4*)&lA[(p * 256 + tid) * 8] = w;
      }
    }
    __syncthreads();
#pragma unroll
    for (int s = 0; s < 4; s++) {
      short8 af[4], bfr[4];
#pragma unroll
      for (int i = 0; i < 4; i++)
        af[i] = *(const short8*)&lA[(wr * 64 + i * 16 + lrow) * 128 + s * 32 + lquad * 8];
#pragma unroll
      for (int j = 0; j < 4; j++)
        bfr[j] = *(const short8*)&lB[(wc * 64 + j * 16 + lrow) * 128 + s * 32 + lquad * 8];
#pragma unroll
      for (int i = 0; i < 4; i++)
#pragma unroll
        for (int j = 0; j < 4; j++)
          acc[i][j] = __builtin_amdgcn_mfma_f32_16x16x32_bf16(af[i], bfr[j], acc[i][j], 0, 0, 0);
    }
    __syncthreads();
  }

  // ---- epilogue A: init qn accumulator + load per-slice proto norms ----
  if (tid < 128) qnf[tid] = 0.f;
  if (tid < 64) pnl[tid] = pnorm_part[slice * 64 + tid];
  __syncthreads();

  // ---- epilogue B: z -> LDS bf16 (128 x 128) + per-row slice norms ----
#pragma unroll
  for (int i = 0; i < 4; i++) {
    float rn[4] = {0.f, 0.f, 0.f, 0.f};
#pragma unroll
    for (int j = 0; j < 4; j++) {
      int col = wc * 64 + j * 16 + lrow;              // local d (0..127)
      float bb = b[n0 + col];
#pragma unroll
      for (int r = 0; r < 4; r++) {
        int row = wr * 64 + i * 16 + lquad * 4 + r;   // local q (0..127)
        float v = acc[i][j][r] + bb;
        unsigned short h = f2bf(v);
        zs[row * ZS_LD + col] = h;
        float vq = bf2f(h);
        rn[r] += vq * vq;
      }
    }
#pragma unroll
    for (int r = 0; r < 4; r++) {
      float s2 = rn[r];
      s2 += __shfl_xor(s2, 1, 16);
      s2 += __shfl_xor(s2, 2, 16);
      s2 += __shfl_xor(s2, 4, 16);
      s2 += __shfl_xor(s2, 8, 16);
      if (lrow == 0) atomicAdd(&qnf[wr * 64 + i * 16 + lquad * 4 + r], s2);
    }
  }
  __syncthreads();

  // ---- epilogue C: S = zs(128x128) @ proto_slice(64x128)^T; wave -> 32 rows.
  //      proto B-frags straight from global (proto_bf is 64KB, L2-hot). ----
  floatx4 acc2[2][4];
#pragma unroll
  for (int i = 0; i < 2; i++)
#pragma unroll
    for (int j = 0; j < 4; j++) acc2[i][j] = (floatx4){0.f, 0.f, 0.f, 0.f};

#pragma unroll
  for (int ks = 0; ks < 4; ks++) {
    short8 af2[2], bp[4];
#pragma unroll
    for (int i = 0; i < 2; i++)
      af2[i] = *(const short8*)&zs[(wave * 32 + i * 16 + lrow) * ZS_LD + ks * 32 + lquad * 8];
#pragma unroll
    for (int j = 0; j < 4; j++)
      bp[j] = *(const short8*)&proto_bf[(size_t)(j * 16 + lrow) * D_DIM + n0 + ks * 32 + lquad * 8];
#pragma unroll
    for (int i = 0; i < 2; i++)
#pragma unroll
      for (int j = 0; j < 4; j++)
        acc2[i][j] = __builtin_amdgcn_mfma_f32_16x16x32_bf16(af2[i], bp[j], acc2[i][j], 0, 0, 0);
  }

  // ---- epilogue D: out += 2S - qn_slice - pn_slice ----
  size_t qbase = (size_t)mt * 128;
#pragma unroll
  for (int i = 0; i < 2; i++) {
#pragma unroll
    for (int j = 0; j < 4; j++) {
      int c = j * 16 + lrow;
      float pn = pnl[c];
#pragma unroll
      for (int r = 0; r < 4; r++) {
        int ql = wave * 32 + i * 16 + lquad * 4 + r;
        float val = 2.f * acc2[i][j][r] - qnf[ql] - pn;
        atomicAdd(&out[(qbase + ql) * NWAY + c], val);
      }
    }
  }
}

extern "C" void kernel_launch(void* const* d_in, const int* in_sizes, int n_in,
                              void* d_out, int out_size, void* d_ws, size_t ws_size,
                              hipStream_t stream) {
  const float* xs = (const float*)d_in[0];
  const int* ys = (const int*)d_in[1];
  const float* xq = (const float*)d_in[2];
  const float* W = (const float*)d_in[3];
  const float* b = (const float*)d_in[4];
  float* out = (float*)d_out;
  char* ws = (char*)d_ws;

  size_t off = 0;
  auto take = [&](size_t bytes) -> char* {
    char* r = ws + off;
    off += (bytes + 255) & ~(size_t)255;
    return r;
  };
  unsigned short* Wt = (unsigned short*)take((size_t)D_DIM * F_DIM * 2);       // 2 MB
  float* csum = (float*)take((size_t)NWAY * F_DIM * 4);                        // 512 KB
  unsigned short* proto_bf = (unsigned short*)take((size_t)NWAY * D_DIM * 2);  // 64 KB
  float* counts = (float*)take(NWAY * 4);
  float* pnorm_part = (float*)take(4 * NWAY * 4);
  int* order = (int*)take(S_ROWS * 4);
  int* starts = (int*)take((NWAY + 1) * 4);
  size_t base_off = off;
  unsigned short* xqb = (unsigned short*)take((size_t)Q_ROWS * F_DIM * 2);     // 67 MB

  if (base_off > ws_size) return;             // can't run at all
  bool adma = (off <= ws_size);               // enough room for bf16 xq?

  if (adma) {
    k_prep<<<257 + 4096, 256, 0, stream>>>(W, Wt, out, pnorm_part, ys, order,
                                           starts, counts, xq, xqb);
  } else {
    k_prep<<<257, 256, 0, stream>>>(W, Wt, out, pnorm_part, ys, order,
                                    starts, counts, xq, (unsigned short*)0);
  }
  k1_csum<<<128, 256, 0, stream>>>(xs, order, starts, csum);
  k2_full<<<64, 256, 0, stream>>>(W, csum, b, counts, proto_bf, pnorm_part);
  if (adma) {
    k3_fused<1><<<512, 256, 0, stream>>>(xq, xqb, Wt, b, proto_bf, pnorm_part, out);
  } else {
    k3_fused<0><<<512, 256, 0, stream>>>(xq, xqb, Wt, b, proto_bf, pnorm_part, out);
  }
}

// Round 7
// 360.694 us; speedup vs baseline: 1.0611x; 1.0611x over previous
//
#include <hip/hip_runtime.h>

// ProtoNet: out[q][n] = -|| (xq[q]@W + b) - proto[n] ||^2
// v7: counted-vmcnt pipelined GEMM (T3+T4): raw s_barrier + s_waitcnt vmcnt(4)
// keeps next-tile B-DMAs in flight across the barrier (never drain to 0).
// + XOR LDS swizzle (T2; pays only in this regime) + setprio (T5).
//   k_prep : transpose W -> Wt bf16; zero out + pnorm_part; bin ys
//   k1_csum: per-class support sums (f32)            -> csum [64][2048]
//   k2_full: proto = csum@W/cnt + b in one shot      -> proto_bf + pnorm_part
//   k3_fused: z = xq@W + b (128x128, BK=64, 4 waves, 2-deep B prefetch)
//             + fused distance epilogue, atomicAdd into pre-zeroed out.

typedef __attribute__((ext_vector_type(8))) short short8;
typedef __attribute__((ext_vector_type(4))) float floatx4;

#define S_ROWS 1024
#define F_DIM  2048
#define D_DIM  512
#define NWAY   64
#define Q_ROWS 16384
#define ZS_LD  136
#define NSTEP  32

static __device__ __forceinline__ unsigned short f2bf(float f) {
  unsigned int u = __float_as_uint(f);
  u += 0x7FFF + ((u >> 16) & 1);   // RNE
  return (unsigned short)(u >> 16);
}
static __device__ __forceinline__ float bf2f(unsigned short s) {
  return __uint_as_float(((unsigned int)s) << 16);
}
// pack two floats -> two bf16 (round-half-up; ties-only deviation from RNE)
static __device__ __forceinline__ unsigned int pack_bf2(float x, float y) {
  unsigned int ux = __float_as_uint(x) + 0x8000u;
  unsigned int uy = __float_as_uint(y) + 0x8000u;
  return __builtin_amdgcn_perm(uy, ux, 0x07060302u);  // hi16(uy)<<16 | hi16(ux)
}
// async global->LDS, 16B per lane. LDS dest = wave-uniform base + lane*16.
static __device__ __forceinline__ void load_lds16(const unsigned short* g, unsigned short* l) {
  __builtin_amdgcn_global_load_lds((const __attribute__((address_space(1))) unsigned int*)g,
                                   (__attribute__((address_space(3))) unsigned int*)l,
                                   16, 0, 0);
}

// ---- k_prep: blocks 0..255 transpose W + zero their slice of out;
//      block 256 bins support ids by class + zeroes pnorm_part ----
__global__ __launch_bounds__(256) void k_prep(const float* __restrict__ W,
                                              unsigned short* __restrict__ Wt,
                                              float* __restrict__ outz,
                                              float* __restrict__ pnorm_part,
                                              const int* __restrict__ ys,
                                              int* __restrict__ order,
                                              int* __restrict__ starts,
                                              float* __restrict__ counts) {
  __shared__ unsigned short t[64][65];
  __shared__ int cnt[NWAY];
  __shared__ int st[NWAY + 1];
  __shared__ int wp[NWAY];
  int bx = blockIdx.x;
  int tid = threadIdx.x;
  if (bx < 256) {
    float4 zz = {0.f, 0.f, 0.f, 0.f};
#pragma unroll
    for (int p = 0; p < 4; p++)
      *(float4*)&outz[(size_t)bx * 4096 + p * 1024 + tid * 4] = zz;
    int f0 = (bx >> 3) << 6;   // 32 f-tiles
    int d0 = (bx & 7) << 6;    // 8 d-tiles
    for (int j = 0; j < 16; j++) {
      int lin = j * 256 + tid;
      int fl = lin >> 6, dl = lin & 63;
      t[fl][dl] = f2bf(W[(size_t)(f0 + fl) * D_DIM + d0 + dl]);
    }
    __syncthreads();
    for (int j = 0; j < 16; j++) {
      int lin = j * 256 + tid;
      int dl = lin >> 6, fl = lin & 63;
      Wt[(size_t)(d0 + dl) * F_DIM + f0 + fl] = t[fl][dl];
    }
  } else {
    pnorm_part[tid] = 0.f;   // 256 entries = [4 slices][64 classes]
    if (tid < NWAY) cnt[tid] = 0;
    __syncthreads();
    for (int j = tid; j < S_ROWS; j += 256) atomicAdd(&cnt[ys[j]], 1);
    __syncthreads();
    if (tid == 0) {
      int a = 0;
      for (int c = 0; c < NWAY; c++) { st[c] = a; wp[c] = a; a += cnt[c]; }
      st[NWAY] = a;
    }
    __syncthreads();
    for (int j = tid; j < S_ROWS; j += 256) {
      int c = ys[j];
      int p = atomicAdd(&wp[c], 1);
      order[p] = j;
    }
    if (tid < NWAY) counts[tid] = (float)cnt[tid];
    if (tid < NWAY + 1) starts[tid] = st[tid];
  }
}

// ---- K1: class sums. grid = 64 classes x 2 f-tiles; float4 per thread ----
__global__ __launch_bounds__(256) void k1_csum(const float* __restrict__ xs,
                                               const int* __restrict__ order,
                                               const int* __restrict__ starts,
                                               float* __restrict__ csum) {
  __shared__ int lord[S_ROWS];
  int c = blockIdx.x >> 1;
  int tid = threadIdx.x;
  int s = starts[c], e = starts[c + 1];
  int len = e - s;
  for (int j = tid; j < len; j += 256) lord[j] = order[s + j];
  __syncthreads();
  int f0 = (blockIdx.x & 1) * 1024 + tid * 4;
  float4 a = {0.f, 0.f, 0.f, 0.f};
  for (int i = 0; i < len; i++) {
    float4 v = *(const float4*)&xs[(size_t)lord[i] * F_DIM + f0];
    a.x += v.x; a.y += v.y; a.z += v.z; a.w += v.w;
  }
  *(float4*)&csum[(size_t)c * F_DIM + f0] = a;
}

// ---- k2_full: proto in one shot. grid = 8 class-groups x 8 d-chunks = 64. ----
__global__ __launch_bounds__(256) void k2_full(const float* __restrict__ W,
                                               const float* __restrict__ csum,
                                               const float* __restrict__ b,
                                               const float* __restrict__ counts,
                                               unsigned short* __restrict__ proto_bf,
                                               float* __restrict__ pnorm_part) {
  __shared__ __align__(16) float wch[64 * 64];   // 16 KB
  __shared__ float csl[8 * 64];                  // 2 KB
  int bx = blockIdx.x;
  int cg = bx >> 3, dc = bx & 7;
  int c0 = cg * 8, d0 = dc * 64;
  int tid = threadIdx.x;
  int cl = tid >> 5;          // local class 0..7
  int dl = (tid & 31) * 2;    // local d col pair
  float a0 = 0.f, a1 = 0.f;
  for (int fs = 0; fs < 32; fs++) {
    int f0 = fs * 64;
    __syncthreads();
    for (int idx = tid; idx < 4096; idx += 256) {
      int r = idx >> 6, q = idx & 63;
      wch[idx] = W[(size_t)(f0 + r) * D_DIM + d0 + q];
    }
    for (int idx = tid; idx < 512; idx += 256) {
      int r = idx >> 6, q = idx & 63;
      csl[idx] = csum[(size_t)(c0 + r) * F_DIM + f0 + q];
    }
    __syncthreads();
#pragma unroll 8
    for (int f = 0; f < 64; f++) {
      float s = csl[cl * 64 + f];
      a0 += s * wch[f * 64 + dl];
      a1 += s * wch[f * 64 + dl + 1];
    }
  }
  int c = c0 + cl;
  float cntv = counts[c];
  float inv = 1.f / fmaxf(cntv, 1.f);
  float p0 = (a0 + cntv * b[d0 + dl]) * inv;     // cnt==0 -> 0, matches ref
  float p1 = (a1 + cntv * b[d0 + dl + 1]) * inv;
  unsigned short h0 = f2bf(p0), h1 = f2bf(p1);
  proto_bf[(size_t)c * D_DIM + d0 + dl] = h0;
  proto_bf[(size_t)c * D_DIM + d0 + dl + 1] = h1;
  float q0 = bf2f(h0), q1 = bf2f(h1);
  float s2 = q0 * q0 + q1 * q1;
  s2 += __shfl_xor(s2, 1, 32);
  s2 += __shfl_xor(s2, 2, 32);
  s2 += __shfl_xor(s2, 4, 32);
  s2 += __shfl_xor(s2, 8, 32);
  s2 += __shfl_xor(s2, 16, 32);
  if ((tid & 31) == 0) atomicAdd(&pnorm_part[(dc >> 1) * 64 + c], s2);
}

// ---- k3_fused: 128x128 z-tile GEMM, BK=64, 4 waves, counted-vmcnt pipeline:
//      B 4-buf / 2-deep DMA prefetch; A 2-buf reg-pack (issue-early/write-late).
//      XOR chunk swizzle on A (ds_write side) and B (pre-swizzled DMA source).
//      grid = 128 m-tiles x 4 n-slices = 512 blocks, 1 block/CU. ----
__global__ __launch_bounds__(256) void k3_fused(const float* __restrict__ xq,
                                                const unsigned short* __restrict__ Wt,
                                                const float* __restrict__ b,
                                                const unsigned short* __restrict__ proto_bf,
                                                const float* __restrict__ pnorm_part,
                                                float* __restrict__ out) {
  // LDS: lA 2 x 16KB @0; lB 4 x 16KB @32768; epilogue zs overlays lB;
  // qnf @98304 (512B), pnl @98816 (256B). Total 99072 -> 1 block/CU.
  __shared__ __align__(16) char smem[99072];
  unsigned short* lA = (unsigned short*)smem;
  unsigned short* lB = (unsigned short*)(smem + 32768);
  unsigned short* zs = (unsigned short*)(smem + 32768);
  float* qnf = (float*)(smem + 98304);
  float* pnl = (float*)(smem + 98816);

  int tid = threadIdx.x;
  int bx = blockIdx.x;
  // XCD swizzle (512 % 8 == 0, bijective)
  int xcd = bx & 7;
  int wg = xcd * 64 + (bx >> 3);
  int mt = wg >> 2;                 // 0..127
  int slice = wg & 3;
  int n0 = slice * 128;
  int m0 = mt * 128;

  int wave = tid >> 6, lane = tid & 63;
  int wr = wave >> 1, wc = wave & 1;
  int lrow = lane & 15, lquad = lane >> 4;
  int rsw = lrow & 7;               // read-side XOR key

  floatx4 acc[4][4];
#pragma unroll
  for (int i = 0; i < 4; i++)
#pragma unroll
    for (int j = 0; j < 4; j++) acc[i][j] = (floatx4){0.f, 0.f, 0.f, 0.f};

  // staging maps (BK=64, chunk=16B=8 halfs, 8 chunks/row):
  int srow = tid >> 3;              // base row 0..31 (+p*32 / +i*32)
  int skq = tid & 7;                // linear chunk pos within row
  int sswz = srow & 7;              // write-side XOR key ((p|i)*32 ≡ 0 mod 8)
  const float* ag = xq + (size_t)(m0 + srow) * F_DIM + skq * 8;
  // B source pre-swizzled: LDS pos (row,skq) must hold global chunk skq^row&7
  const unsigned short* bg = Wt + (size_t)(n0 + srow) * F_DIM + (skq ^ sswz) * 8;

  float4 pf[4][2];   // A prefetch registers (32 VGPR)

#define STAGE_B(kstep, buf)                                                     \
  {                                                                             \
    _Pragma("unroll") for (int i_ = 0; i_ < 4; i_++)                            \
        load_lds16(bg + (size_t)i_ * 32 * F_DIM + (kstep) * 64,                 \
                   &lB[(size_t)(buf) * 8192 + (i_ * 256 + wave * 64) * 8]);     \
  }
#define ISSUE_A(kstep)                                                          \
  {                                                                             \
    _Pragma("unroll") for (int p_ = 0; p_ < 4; p_++) {                          \
      const float* gp_ = ag + (size_t)p_ * 32 * F_DIM + (kstep) * 64;           \
      pf[p_][0] = *(const float4*)gp_;                                          \
      pf[p_][1] = *(const float4*)(gp_ + 4);                                    \
    }                                                                           \
  }
#define WRITE_A(buf)                                                            \
  {                                                                             \
    _Pragma("unroll") for (int p_ = 0; p_ < 4; p_++) {                          \
      uint4 w_;                                                                 \
      w_.x = pack_bf2(pf[p_][0].x, pf[p_][0].y);                                \
      w_.y = pack_bf2(pf[p_][0].z, pf[p_][0].w);                                \
      w_.z = pack_bf2(pf[p_][1].x, pf[p_][1].y);                                \
      w_.w = pack_bf2(pf[p_][1].z, pf[p_][1].w);                                \
      *(uint4*)&lA[(size_t)(buf) * 8192 + ((p_ * 32 + srow) * 64 +              \
                                           ((skq ^ sswz) * 8))] = w_;           \
    }                                                                           \
  }
#define COMPUTE(ca, cb)                                                         \
  {                                                                             \
    _Pragma("unroll") for (int s_ = 0; s_ < 2; s_++) {                          \
      short8 af_[4], bf_[4];                                                    \
      int cx_ = ((s_ * 4 + lquad) ^ rsw) * 8;                                   \
      _Pragma("unroll") for (int i_ = 0; i_ < 4; i_++)                          \
          af_[i_] = *(const short8*)&lA[(size_t)(ca) * 8192 +                   \
                                        (wr * 64 + i_ * 16 + lrow) * 64 + cx_]; \
      _Pragma("unroll") for (int j_ = 0; j_ < 4; j_++)                          \
          bf_[j_] = *(const short8*)&lB[(size_t)(cb) * 8192 +                   \
                                        (wc * 64 + j_ * 16 + lrow) * 64 + cx_]; \
      __builtin_amdgcn_s_setprio(1);                                            \
      _Pragma("unroll") for (int i_ = 0; i_ < 4; i_++)                          \
          _Pragma("unroll") for (int j_ = 0; j_ < 4; j_++)                      \
              acc[i_][j_] = __builtin_amdgcn_mfma_f32_16x16x32_bf16(            \
                  af_[i_], bf_[j_], acc[i_][j_], 0, 0, 0);                      \
      __builtin_amdgcn_s_setprio(0);                                            \
    }                                                                           \
  }

  // prologue: B(0)->buf0; A(0) packed to lA0; B(1)->buf1; wait B(0) only.
  STAGE_B(0, 0);
  ISSUE_A(0);
  WRITE_A(0);
  STAGE_B(1, 1);
  asm volatile("s_waitcnt lgkmcnt(0)" ::: "memory");
  asm volatile("s_waitcnt vmcnt(4)" ::: "memory");
  __builtin_amdgcn_s_barrier();
  __builtin_amdgcn_sched_barrier(0);

  for (int t = 0; t < NSTEP; ++t) {
    int cb = t & 3, ca = t & 1;
    if (t + 2 < NSTEP) STAGE_B(t + 2, (t + 2) & 3);
    if (t + 1 < NSTEP) ISSUE_A(t + 1);
    COMPUTE(ca, cb);
    if (t + 1 < NSTEP) WRITE_A((t + 1) & 1);
    asm volatile("s_waitcnt lgkmcnt(0)" ::: "memory");
    if (t + 2 < NSTEP) {
      asm volatile("s_waitcnt vmcnt(4)" ::: "memory");   // leave t+2's 4 in flight
    } else {
      asm volatile("s_waitcnt vmcnt(0)" ::: "memory");
    }
    __builtin_amdgcn_s_barrier();
    __builtin_amdgcn_sched_barrier(0);
  }

  // ---- epilogue A: init qn accumulator + load per-slice proto norms ----
  __syncthreads();
  if (tid < 128) qnf[tid] = 0.f;
  if (tid < 64) pnl[tid] = pnorm_part[slice * 64 + tid];
  __syncthreads();

  // ---- epilogue B: z -> LDS bf16 (128 x 128) + per-row slice norms ----
#pragma unroll
  for (int i = 0; i < 4; i++) {
    float rn[4] = {0.f, 0.f, 0.f, 0.f};
#pragma unroll
    for (int j = 0; j < 4; j++) {
      int col = wc * 64 + j * 16 + lrow;              // local d (0..127)
      float bb = b[n0 + col];
#pragma unroll
      for (int r = 0; r < 4; r++) {
        int row = wr * 64 + i * 16 + lquad * 4 + r;   // local q (0..127)
        float v = acc[i][j][r] + bb;
        unsigned short h = f2bf(v);
        zs[row * ZS_LD + col] = h;
        float vq = bf2f(h);
        rn[r] += vq * vq;
      }
    }
#pragma unroll
    for (int r = 0; r < 4; r++) {
      float s2 = rn[r];
      s2 += __shfl_xor(s2, 1, 16);
      s2 += __shfl_xor(s2, 2, 16);
      s2 += __shfl_xor(s2, 4, 16);
      s2 += __shfl_xor(s2, 8, 16);
      if (lrow == 0) atomicAdd(&qnf[wr * 64 + i * 16 + lquad * 4 + r], s2);
    }
  }
  __syncthreads();

  // ---- epilogue C: S = zs(128x128) @ proto_slice(64x128)^T; wave -> 32 rows ----
  floatx4 acc2[2][4];
#pragma unroll
  for (int i = 0; i < 2; i++)
#pragma unroll
    for (int j = 0; j < 4; j++) acc2[i][j] = (floatx4){0.f, 0.f, 0.f, 0.f};

#pragma unroll
  for (int ks = 0; ks < 4; ks++) {
    short8 af2[2], bp[4];
#pragma unroll
    for (int i = 0; i < 2; i++)
      af2[i] = *(const short8*)&zs[(wave * 32 + i * 16 + lrow) * ZS_LD + ks * 32 + lquad * 8];
#pragma unroll
    for (int j = 0; j < 4; j++)
      bp[j] = *(const short8*)&proto_bf[(size_t)(j * 16 + lrow) * D_DIM + n0 + ks * 32 + lquad * 8];
#pragma unroll
    for (int i = 0; i < 2; i++)
#pragma unroll
      for (int j = 0; j < 4; j++)
        acc2[i][j] = __builtin_amdgcn_mfma_f32_16x16x32_bf16(af2[i], bp[j], acc2[i][j], 0, 0, 0);
  }

  // ---- epilogue D: out += 2S - qn_slice - pn_slice ----
  size_t qbase = (size_t)mt * 128;
#pragma unroll
  for (int i = 0; i < 2; i++) {
#pragma unroll
    for (int j = 0; j < 4; j++) {
      int c = j * 16 + lrow;
      float pn = pnl[c];
#pragma unroll
      for (int r = 0; r < 4; r++) {
        int ql = wave * 32 + i * 16 + lquad * 4 + r;
        float val = 2.f * acc2[i][j][r] - qnf[ql] - pn;
        atomicAdd(&out[(qbase + ql) * NWAY + c], val);
      }
    }
  }
}

extern "C" void kernel_launch(void* const* d_in, const int* in_sizes, int n_in,
                              void* d_out, int out_size, void* d_ws, size_t ws_size,
                              hipStream_t stream) {
  const float* xs = (const float*)d_in[0];
  const int* ys = (const int*)d_in[1];
  const float* xq = (const float*)d_in[2];
  const float* W = (const float*)d_in[3];
  const float* b = (const float*)d_in[4];
  float* out = (float*)d_out;
  char* ws = (char*)d_ws;

  size_t off = 0;
  auto take = [&](size_t bytes) -> char* {
    char* r = ws + off;
    off += (bytes + 255) & ~(size_t)255;
    return r;
  };
  unsigned short* Wt = (unsigned short*)take((size_t)D_DIM * F_DIM * 2);       // 2 MB
  float* csum = (float*)take((size_t)NWAY * F_DIM * 4);                        // 512 KB
  unsigned short* proto_bf = (unsigned short*)take((size_t)NWAY * D_DIM * 2);  // 64 KB
  float* counts = (float*)take(NWAY * 4);
  float* pnorm_part = (float*)take(4 * NWAY * 4);
  int* order = (int*)take(S_ROWS * 4);
  int* starts = (int*)take((NWAY + 1) * 4);

  // Workspace guard: fail cleanly rather than corrupt device memory.
  if (off > ws_size) return;

  k_prep<<<257, 256, 0, stream>>>(W, Wt, out, pnorm_part, ys, order, starts, counts);
  k1_csum<<<128, 256, 0, stream>>>(xs, order, starts, csum);
  k2_full<<<64, 256, 0, stream>>>(W, csum, b, counts, proto_bf, pnorm_part);
  k3_fused<<<512, 256, 0, stream>>>(xq, Wt, b, proto_bf, pnorm_part, out);
}

// Round 8
// 326.006 us; speedup vs baseline: 1.1740x; 1.1064x over previous
//
#include <hip/hip_runtime.h>

// ProtoNet: out[q][n] = -|| (xq[q]@W + b) - proto[n] ||^2
// v8: v7 with the two regressions fixed:
//  (1) ISSUE_A before STAGE_B(t+2) so WRITE_A's implicit vmcnt wait no longer
//      drains the prefetch DMAs (vmcnt is FIFO; A must be OLDER than B(t+2)).
//  (2) lB 4buf->3buf: LDS 99KB->80KB = exactly 2 blocks/CU -> 8 waves/CU.
// Keeps: XOR swizzle (verified r7: conflicts 1.26e7->6.5e4), counted vmcnt(4),
// setprio, XCD swizzle, fused distance epilogue.

typedef __attribute__((ext_vector_type(8))) short short8;
typedef __attribute__((ext_vector_type(4))) float floatx4;

#define S_ROWS 1024
#define F_DIM  2048
#define D_DIM  512
#define NWAY   64
#define Q_ROWS 16384
#define ZS_LD  136
#define NSTEP  32

static __device__ __forceinline__ unsigned short f2bf(float f) {
  unsigned int u = __float_as_uint(f);
  u += 0x7FFF + ((u >> 16) & 1);   // RNE
  return (unsigned short)(u >> 16);
}
static __device__ __forceinline__ float bf2f(unsigned short s) {
  return __uint_as_float(((unsigned int)s) << 16);
}
// pack two floats -> two bf16 (round-half-up; ties-only deviation from RNE)
static __device__ __forceinline__ unsigned int pack_bf2(float x, float y) {
  unsigned int ux = __float_as_uint(x) + 0x8000u;
  unsigned int uy = __float_as_uint(y) + 0x8000u;
  return __builtin_amdgcn_perm(uy, ux, 0x07060302u);  // hi16(uy)<<16 | hi16(ux)
}
// async global->LDS, 16B per lane. LDS dest = wave-uniform base + lane*16.
static __device__ __forceinline__ void load_lds16(const unsigned short* g, unsigned short* l) {
  __builtin_amdgcn_global_load_lds((const __attribute__((address_space(1))) unsigned int*)g,
                                   (__attribute__((address_space(3))) unsigned int*)l,
                                   16, 0, 0);
}

// ---- k_prep: blocks 0..255 transpose W + zero their slice of out;
//      block 256 bins support ids by class + zeroes pnorm_part ----
__global__ __launch_bounds__(256) void k_prep(const float* __restrict__ W,
                                              unsigned short* __restrict__ Wt,
                                              float* __restrict__ outz,
                                              float* __restrict__ pnorm_part,
                                              const int* __restrict__ ys,
                                              int* __restrict__ order,
                                              int* __restrict__ starts,
                                              float* __restrict__ counts) {
  __shared__ unsigned short t[64][65];
  __shared__ int cnt[NWAY];
  __shared__ int st[NWAY + 1];
  __shared__ int wp[NWAY];
  int bx = blockIdx.x;
  int tid = threadIdx.x;
  if (bx < 256) {
    float4 zz = {0.f, 0.f, 0.f, 0.f};
#pragma unroll
    for (int p = 0; p < 4; p++)
      *(float4*)&outz[(size_t)bx * 4096 + p * 1024 + tid * 4] = zz;
    int f0 = (bx >> 3) << 6;   // 32 f-tiles
    int d0 = (bx & 7) << 6;    // 8 d-tiles
    for (int j = 0; j < 16; j++) {
      int lin = j * 256 + tid;
      int fl = lin >> 6, dl = lin & 63;
      t[fl][dl] = f2bf(W[(size_t)(f0 + fl) * D_DIM + d0 + dl]);
    }
    __syncthreads();
    for (int j = 0; j < 16; j++) {
      int lin = j * 256 + tid;
      int dl = lin >> 6, fl = lin & 63;
      Wt[(size_t)(d0 + dl) * F_DIM + f0 + fl] = t[fl][dl];
    }
  } else {
    pnorm_part[tid] = 0.f;   // 256 entries = [4 slices][64 classes]
    if (tid < NWAY) cnt[tid] = 0;
    __syncthreads();
    for (int j = tid; j < S_ROWS; j += 256) atomicAdd(&cnt[ys[j]], 1);
    __syncthreads();
    if (tid == 0) {
      int a = 0;
      for (int c = 0; c < NWAY; c++) { st[c] = a; wp[c] = a; a += cnt[c]; }
      st[NWAY] = a;
    }
    __syncthreads();
    for (int j = tid; j < S_ROWS; j += 256) {
      int c = ys[j];
      int p = atomicAdd(&wp[c], 1);
      order[p] = j;
    }
    if (tid < NWAY) counts[tid] = (float)cnt[tid];
    if (tid < NWAY + 1) starts[tid] = st[tid];
  }
}

// ---- K1: class sums. grid = 64 classes x 2 f-tiles; float4 per thread ----
__global__ __launch_bounds__(256) void k1_csum(const float* __restrict__ xs,
                                               const int* __restrict__ order,
                                               const int* __restrict__ starts,
                                               float* __restrict__ csum) {
  __shared__ int lord[S_ROWS];
  int c = blockIdx.x >> 1;
  int tid = threadIdx.x;
  int s = starts[c], e = starts[c + 1];
  int len = e - s;
  for (int j = tid; j < len; j += 256) lord[j] = order[s + j];
  __syncthreads();
  int f0 = (blockIdx.x & 1) * 1024 + tid * 4;
  float4 a = {0.f, 0.f, 0.f, 0.f};
  for (int i = 0; i < len; i++) {
    float4 v = *(const float4*)&xs[(size_t)lord[i] * F_DIM + f0];
    a.x += v.x; a.y += v.y; a.z += v.z; a.w += v.w;
  }
  *(float4*)&csum[(size_t)c * F_DIM + f0] = a;
}

// ---- k2_full: proto in one shot. grid = 8 class-groups x 8 d-chunks = 64. ----
__global__ __launch_bounds__(256) void k2_full(const float* __restrict__ W,
                                               const float* __restrict__ csum,
                                               const float* __restrict__ b,
                                               const float* __restrict__ counts,
                                               unsigned short* __restrict__ proto_bf,
                                               float* __restrict__ pnorm_part) {
  __shared__ __align__(16) float wch[64 * 64];   // 16 KB
  __shared__ float csl[8 * 64];                  // 2 KB
  int bx = blockIdx.x;
  int cg = bx >> 3, dc = bx & 7;
  int c0 = cg * 8, d0 = dc * 64;
  int tid = threadIdx.x;
  int cl = tid >> 5;          // local class 0..7
  int dl = (tid & 31) * 2;    // local d col pair
  float a0 = 0.f, a1 = 0.f;
  for (int fs = 0; fs < 32; fs++) {
    int f0 = fs * 64;
    __syncthreads();
    for (int idx = tid; idx < 4096; idx += 256) {
      int r = idx >> 6, q = idx & 63;
      wch[idx] = W[(size_t)(f0 + r) * D_DIM + d0 + q];
    }
    for (int idx = tid; idx < 512; idx += 256) {
      int r = idx >> 6, q = idx & 63;
      csl[idx] = csum[(size_t)(c0 + r) * F_DIM + f0 + q];
    }
    __syncthreads();
#pragma unroll 8
    for (int f = 0; f < 64; f++) {
      float s = csl[cl * 64 + f];
      a0 += s * wch[f * 64 + dl];
      a1 += s * wch[f * 64 + dl + 1];
    }
  }
  int c = c0 + cl;
  float cntv = counts[c];
  float inv = 1.f / fmaxf(cntv, 1.f);
  float p0 = (a0 + cntv * b[d0 + dl]) * inv;     // cnt==0 -> 0, matches ref
  float p1 = (a1 + cntv * b[d0 + dl + 1]) * inv;
  unsigned short h0 = f2bf(p0), h1 = f2bf(p1);
  proto_bf[(size_t)c * D_DIM + d0 + dl] = h0;
  proto_bf[(size_t)c * D_DIM + d0 + dl + 1] = h1;
  float q0 = bf2f(h0), q1 = bf2f(h1);
  float s2 = q0 * q0 + q1 * q1;
  s2 += __shfl_xor(s2, 1, 32);
  s2 += __shfl_xor(s2, 2, 32);
  s2 += __shfl_xor(s2, 4, 32);
  s2 += __shfl_xor(s2, 8, 32);
  s2 += __shfl_xor(s2, 16, 32);
  if ((tid & 31) == 0) atomicAdd(&pnorm_part[(dc >> 1) * 64 + c], s2);
}

// ---- k3_fused: 128x128 z-tile GEMM, BK=64, 4 waves, counted-vmcnt pipeline.
//      lA 2-buf (A reg-pack, write-late), lB 3-buf (2-deep DMA prefetch).
//      LDS 80KB = 2 blocks/CU -> 8 waves/CU. A issued BEFORE B(t+2) so the
//      pack's implicit vmcnt wait leaves B(t+2) in flight (never drain to 0).
//      XOR chunk swizzle both-sides (verified r7). grid = 512 blocks. ----
__global__ __launch_bounds__(256) void k3_fused(const float* __restrict__ xq,
                                                const unsigned short* __restrict__ Wt,
                                                const float* __restrict__ b,
                                                const unsigned short* __restrict__ proto_bf,
                                                const float* __restrict__ pnorm_part,
                                                float* __restrict__ out) {
  // LDS: lA 2 x 16KB @0; lB 3 x 16KB @32768; total 81920 = 160KB/2.
  // Epilogue overlay: zs (34816B) @0; qnf @35072; pnl @35584.
  __shared__ __align__(16) char smem[81920];
  unsigned short* lA = (unsigned short*)smem;
  unsigned short* lB = (unsigned short*)(smem + 32768);
  unsigned short* zs = (unsigned short*)smem;
  float* qnf = (float*)(smem + 35072);
  float* pnl = (float*)(smem + 35584);

  int tid = threadIdx.x;
  int bx = blockIdx.x;
  // XCD swizzle (512 % 8 == 0, bijective)
  int xcd = bx & 7;
  int wg = xcd * 64 + (bx >> 3);
  int mt = wg >> 2;                 // 0..127
  int slice = wg & 3;
  int n0 = slice * 128;
  int m0 = mt * 128;

  int wave = tid >> 6, lane = tid & 63;
  int wr = wave >> 1, wc = wave & 1;
  int lrow = lane & 15, lquad = lane >> 4;
  int rsw = lrow & 7;               // read-side XOR key

  floatx4 acc[4][4];
#pragma unroll
  for (int i = 0; i < 4; i++)
#pragma unroll
    for (int j = 0; j < 4; j++) acc[i][j] = (floatx4){0.f, 0.f, 0.f, 0.f};

  // staging maps (BK=64, chunk=16B=8 halfs, 8 chunks/row):
  int srow = tid >> 3;              // base row 0..31 (+p*32 / +i*32)
  int skq = tid & 7;                // linear chunk pos within row
  int sswz = srow & 7;              // write-side XOR key ((p|i)*32 == 0 mod 8)
  const float* ag = xq + (size_t)(m0 + srow) * F_DIM + skq * 8;
  // B source pre-swizzled: LDS pos (row,skq) holds global chunk skq^(row&7)
  const unsigned short* bg = Wt + (size_t)(n0 + srow) * F_DIM + (skq ^ sswz) * 8;

  float4 pf[4][2];   // A prefetch registers (32 VGPR)

#define STAGE_B(kstep, buf)                                                     \
  {                                                                             \
    _Pragma("unroll") for (int i_ = 0; i_ < 4; i_++)                            \
        load_lds16(bg + (size_t)i_ * 32 * F_DIM + (kstep) * 64,                 \
                   &lB[(size_t)(buf) * 8192 + (i_ * 256 + wave * 64) * 8]);     \
  }
#define ISSUE_A(kstep)                                                          \
  {                                                                             \
    _Pragma("unroll") for (int p_ = 0; p_ < 4; p_++) {                          \
      const float* gp_ = ag + (size_t)p_ * 32 * F_DIM + (kstep) * 64;           \
      pf[p_][0] = *(const float4*)gp_;                                          \
      pf[p_][1] = *(const float4*)(gp_ + 4);                                    \
    }                                                                           \
  }
#define WRITE_A(buf)                                                            \
  {                                                                             \
    _Pragma("unroll") for (int p_ = 0; p_ < 4; p_++) {                          \
      uint4 w_;                                                                 \
      w_.x = pack_bf2(pf[p_][0].x, pf[p_][0].y);                                \
      w_.y = pack_bf2(pf[p_][0].z, pf[p_][0].w);                                \
      w_.z = pack_bf2(pf[p_][1].x, pf[p_][1].y);                                \
      w_.w = pack_bf2(pf[p_][1].z, pf[p_][1].w);                                \
      *(uint4*)&lA[(size_t)(buf) * 8192 + ((p_ * 32 + srow) * 64 +              \
                                           ((skq ^ sswz) * 8))] = w_;           \
    }                                                                           \
  }
#define COMPUTE(ca, cb)                                                         \
  {                                                                             \
    _Pragma("unroll") for (int s_ = 0; s_ < 2; s_++) {                          \
      short8 af_[4], bf_[4];                                                    \
      int cx_ = ((s_ * 4 + lquad) ^ rsw) * 8;                                   \
      _Pragma("unroll") for (int i_ = 0; i_ < 4; i_++)                          \
          af_[i_] = *(const short8*)&lA[(size_t)(ca) * 8192 +                   \
                                        (wr * 64 + i_ * 16 + lrow) * 64 + cx_]; \
      _Pragma("unroll") for (int j_ = 0; j_ < 4; j_++)                          \
          bf_[j_] = *(const short8*)&lB[(size_t)(cb) * 8192 +                   \
                                        (wc * 64 + j_ * 16 + lrow) * 64 + cx_]; \
      __builtin_amdgcn_s_setprio(1);                                            \
      _Pragma("unroll") for (int i_ = 0; i_ < 4; i_++)                          \
          _Pragma("unroll") for (int j_ = 0; j_ < 4; j_++)                      \
              acc[i_][j_] = __builtin_amdgcn_mfma_f32_16x16x32_bf16(            \
                  af_[i_], bf_[j_], acc[i_][j_], 0, 0, 0);                      \
      __builtin_amdgcn_s_setprio(0);                                            \
    }                                                                           \
  }

  // prologue: B(0)->buf0; A(0) to lA0 (drains B(0) too - fine, once);
  // B(1)->buf1 left in flight across the barrier.
  STAGE_B(0, 0);
  ISSUE_A(0);
  WRITE_A(0);
  STAGE_B(1, 1);
  asm volatile("s_waitcnt lgkmcnt(0)" ::: "memory");
  __builtin_amdgcn_s_barrier();
  __builtin_amdgcn_sched_barrier(0);

  int cb = 0;   // lB buffer holding tile t
  for (int t = 0; t < NSTEP; ++t) {
    int ca = t & 1;
    int sb = cb + 2; if (sb >= 3) sb -= 3;        // (t+2) % 3
    if (t + 1 < NSTEP) ISSUE_A(t + 1);            // A first (older in VMEM FIFO)
    if (t + 2 < NSTEP) STAGE_B(t + 2, sb);        // then B prefetch (younger)
    COMPUTE(ca, cb);
    if (t + 1 < NSTEP) WRITE_A(ca ^ 1);           // implicit wait: vmcnt(4)
    asm volatile("s_waitcnt lgkmcnt(0)" ::: "memory");
    if (t + 2 < NSTEP) {
      asm volatile("s_waitcnt vmcnt(4)" ::: "memory");   // B(t+1) landed; B(t+2) in flight
    } else {
      asm volatile("s_waitcnt vmcnt(0)" ::: "memory");
    }
    __builtin_amdgcn_s_barrier();
    __builtin_amdgcn_sched_barrier(0);
    cb = (cb == 2) ? 0 : cb + 1;
  }

  // ---- epilogue A: init qn accumulator + load per-slice proto norms ----
  __syncthreads();
  if (tid < 128) qnf[tid] = 0.f;
  if (tid < 64) pnl[tid] = pnorm_part[slice * 64 + tid];
  __syncthreads();

  // ---- epilogue B: z -> LDS bf16 (128 x 128) + per-row slice norms ----
#pragma unroll
  for (int i = 0; i < 4; i++) {
    float rn[4] = {0.f, 0.f, 0.f, 0.f};
#pragma unroll
    for (int j = 0; j < 4; j++) {
      int col = wc * 64 + j * 16 + lrow;              // local d (0..127)
      float bb = b[n0 + col];
#pragma unroll
      for (int r = 0; r < 4; r++) {
        int row = wr * 64 + i * 16 + lquad * 4 + r;   // local q (0..127)
        float v = acc[i][j][r] + bb;
        unsigned short h = f2bf(v);
        zs[row * ZS_LD + col] = h;
        float vq = bf2f(h);
        rn[r] += vq * vq;
      }
    }
#pragma unroll
    for (int r = 0; r < 4; r++) {
      float s2 = rn[r];
      s2 += __shfl_xor(s2, 1, 16);
      s2 += __shfl_xor(s2, 2, 16);
      s2 += __shfl_xor(s2, 4, 16);
      s2 += __shfl_xor(s2, 8, 16);
      if (lrow == 0) atomicAdd(&qnf[wr * 64 + i * 16 + lquad * 4 + r], s2);
    }
  }
  __syncthreads();

  // ---- epilogue C: S = zs(128x128) @ proto_slice(64x128)^T; wave -> 32 rows ----
  floatx4 acc2[2][4];
#pragma unroll
  for (int i = 0; i < 2; i++)
#pragma unroll
    for (int j = 0; j < 4; j++) acc2[i][j] = (floatx4){0.f, 0.f, 0.f, 0.f};

#pragma unroll
  for (int ks = 0; ks < 4; ks++) {
    short8 af2[2], bp[4];
#pragma unroll
    for (int i = 0; i < 2; i++)
      af2[i] = *(const short8*)&zs[(wave * 32 + i * 16 + lrow) * ZS_LD + ks * 32 + lquad * 8];
#pragma unroll
    for (int j = 0; j < 4; j++)
      bp[j] = *(const short8*)&proto_bf[(size_t)(j * 16 + lrow) * D_DIM + n0 + ks * 32 + lquad * 8];
#pragma unroll
    for (int i = 0; i < 2; i++)
#pragma unroll
      for (int j = 0; j < 4; j++)
        acc2[i][j] = __builtin_amdgcn_mfma_f32_16x16x32_bf16(af2[i], bp[j], acc2[i][j], 0, 0, 0);
  }

  // ---- epilogue D: out += 2S - qn_slice - pn_slice ----
  size_t qbase = (size_t)mt * 128;
#pragma unroll
  for (int i = 0; i < 2; i++) {
#pragma unroll
    for (int j = 0; j < 4; j++) {
      int c = j * 16 + lrow;
      float pn = pnl[c];
#pragma unroll
      for (int r = 0; r < 4; r++) {
        int ql = wave * 32 + i * 16 + lquad * 4 + r;
        float val = 2.f * acc2[i][j][r] - qnf[ql] - pn;
        atomicAdd(&out[(qbase + ql) * NWAY + c], val);
      }
    }
  }
}

extern "C" void kernel_launch(void* const* d_in, const int* in_sizes, int n_in,
                              void* d_out, int out_size, void* d_ws, size_t ws_size,
                              hipStream_t stream) {
  const float* xs = (const float*)d_in[0];
  const int* ys = (const int*)d_in[1];
  const float* xq = (const float*)d_in[2];
  const float* W = (const float*)d_in[3];
  const float* b = (const float*)d_in[4];
  float* out = (float*)d_out;
  char* ws = (char*)d_ws;

  size_t off = 0;
  auto take = [&](size_t bytes) -> char* {
    char* r = ws + off;
    off += (bytes + 255) & ~(size_t)255;
    return r;
  };
  unsigned short* Wt = (unsigned short*)take((size_t)D_DIM * F_DIM * 2);       // 2 MB
  float* csum = (float*)take((size_t)NWAY * F_DIM * 4);                        // 512 KB
  unsigned short* proto_bf = (unsigned short*)take((size_t)NWAY * D_DIM * 2);  // 64 KB
  float* counts = (float*)take(NWAY * 4);
  float* pnorm_part = (float*)take(4 * NWAY * 4);
  int* order = (int*)take(S_ROWS * 4);
  int* starts = (int*)take((NWAY + 1) * 4);

  // Workspace guard: fail cleanly rather than corrupt device memory.
  if (off > ws_size) return;

  k_prep<<<257, 256, 0, stream>>>(W, Wt, out, pnorm_part, ys, order, starts, counts);
  k1_csum<<<128, 256, 0, stream>>>(xs, order, starts, csum);
  k2_full<<<64, 256, 0, stream>>>(W, csum, b, counts, proto_bf, pnorm_part);
  k3_fused<<<512, 256, 0, stream>>>(xq, Wt, b, proto_bf, pnorm_part, out);
}